// Round 1
// baseline (424.605 us; speedup 1.0000x reference)
//
#include <hip/hip_runtime.h>
#include <math.h>

// Problem constants (from reference)
constexpr int N_NODES = 100000;
constexpr int N_EDGES = 3200000;
constexpr int NF      = 6;

// d_ws layout (floats):
//   [0,        N)    v_re
//   [N,       2N)    v_im
//   [2N,      3N)    mv_re   (segment-sum accumulator, must be zeroed)
//   [3N,      4N)    mv_im   (zeroed)
//   [4N,   4N+3)     sums: sum|diff|, sum|re|, sum|im|   (zeroed)

__global__ void node_prep(const float* __restrict__ pred,
                          const float* __restrict__ target,
                          const unsigned char* __restrict__ mask,
                          float* __restrict__ v_re,
                          float* __restrict__ v_im) {
    int i = blockIdx.x * blockDim.x + threadIdx.x;
    if (i >= N_NODES) return;
    const int b = i * NF;
    float vm = mask[b + 0] ? pred[b + 0] : target[b + 0];
    float va = mask[b + 1] ? pred[b + 1] : target[b + 1];
    float s, c;
    sincosf(va, &s, &c);
    v_re[i] = vm * c;
    v_im[i] = vm * s;
}

__global__ void edge_scatter(const int* __restrict__ row,
                             const int* __restrict__ col,
                             const float2* __restrict__ attr,   // (G,B) per edge
                             const float* __restrict__ v_re,
                             const float* __restrict__ v_im,
                             float* __restrict__ mv_re,
                             float* __restrict__ mv_im) {
    int e = blockIdx.x * blockDim.x + threadIdx.x;
    if (e >= N_EDGES) return;
    int r = row[e];
    int c = col[e];
    float2 gb = attr[e];
    float vr = v_re[c];
    float vi = v_im[c];
    // (G - iB) * (vr - i*vi) = (G*vr - B*vi) + i * ( -(G*vi + B*vr) )
    float mre = fmaf(gb.x, vr, -gb.y * vi);
    float mim = -fmaf(gb.x, vi, gb.y * vr);
    atomicAdd(&mv_re[r], mre);
    atomicAdd(&mv_im[r], mim);
}

__global__ void finalize_nodes(const float* __restrict__ pred,
                               const float* __restrict__ target,
                               const unsigned char* __restrict__ mask,
                               const float* __restrict__ v_re,
                               const float* __restrict__ v_im,
                               const float* __restrict__ mv_re,
                               const float* __restrict__ mv_im,
                               float* __restrict__ sums) {
    int i = blockIdx.x * blockDim.x + threadIdx.x;
    float a = 0.f, ar = 0.f, ai = 0.f;
    if (i < N_NODES) {
        const int b = i * NF;
        float pg = mask[b + 2] ? pred[b + 2] : target[b + 2];
        float qg = mask[b + 3] ? pred[b + 3] : target[b + 3];
        float pd = mask[b + 4] ? pred[b + 4] : target[b + 4];
        float qd = mask[b + 5] ? pred[b + 5] : target[b + 5];
        float netP = pg - pd;
        float netQ = qg - qd;
        float vr = v_re[i], vi = v_im[i];
        float mr = mv_re[i], mi = mv_im[i];
        // S = V * matvec
        float s_re = vr * mr - vi * mi;
        float s_im = vr * mi + vi * mr;
        float dre = netP - s_re;
        float dim = netQ - s_im;
        ar = fabsf(dre);
        ai = fabsf(dim);
        a  = sqrtf(dre * dre + dim * dim);
    }
    // wave-64 reduction
    #pragma unroll
    for (int off = 32; off > 0; off >>= 1) {
        a  += __shfl_down(a,  off, 64);
        ar += __shfl_down(ar, off, 64);
        ai += __shfl_down(ai, off, 64);
    }
    __shared__ float red[3][4];   // 4 waves per 256-thread block
    int wave = threadIdx.x >> 6;
    int lane = threadIdx.x & 63;
    if (lane == 0) { red[0][wave] = a; red[1][wave] = ar; red[2][wave] = ai; }
    __syncthreads();
    if (threadIdx.x == 0) {
        float ta = red[0][0] + red[0][1] + red[0][2] + red[0][3];
        float tr = red[1][0] + red[1][1] + red[1][2] + red[1][3];
        float ti = red[2][0] + red[2][1] + red[2][2] + red[2][3];
        atomicAdd(&sums[0], ta);
        atomicAdd(&sums[1], tr);
        atomicAdd(&sums[2], ti);
    }
}

__global__ void write_out(const float* __restrict__ sums, float* __restrict__ out) {
    if (threadIdx.x == 0 && blockIdx.x == 0) {
        const float inv = 1.0f / (float)N_NODES;
        out[0] = sums[0] * inv;
        out[1] = sums[1] * inv;
        out[2] = sums[2] * inv;
    }
}

extern "C" void kernel_launch(void* const* d_in, const int* in_sizes, int n_in,
                              void* d_out, int out_size, void* d_ws, size_t ws_size,
                              hipStream_t stream) {
    const float*         pred   = (const float*)d_in[0];
    const float*         target = (const float*)d_in[1];
    const int*           eidx   = (const int*)d_in[2];      // (2, N_EDGES)
    const float2*        attr   = (const float2*)d_in[3];   // (N_EDGES, 2)
    const unsigned char* mask   = (const unsigned char*)d_in[4];
    float* out = (float*)d_out;

    float* ws    = (float*)d_ws;
    float* v_re  = ws;
    float* v_im  = ws + (size_t)N_NODES;
    float* mv_re = ws + 2ull * N_NODES;
    float* mv_im = ws + 3ull * N_NODES;
    float* sums  = ws + 4ull * N_NODES;

    const int* row = eidx;             // edge_index[0] = src
    const int* col = eidx + N_EDGES;   // edge_index[1] = dst

    // zero accumulators (mv_re, mv_im, sums)
    hipMemsetAsync(mv_re, 0, (2ull * N_NODES + 3) * sizeof(float), stream);

    const int B = 256;
    node_prep<<<(N_NODES + B - 1) / B, B, 0, stream>>>(pred, target, mask, v_re, v_im);
    edge_scatter<<<(N_EDGES + B - 1) / B, B, 0, stream>>>(row, col, attr, v_re, v_im, mv_re, mv_im);
    finalize_nodes<<<(N_NODES + B - 1) / B, B, 0, stream>>>(pred, target, mask, v_re, v_im,
                                                            mv_re, mv_im, sums);
    write_out<<<1, 64, 0, stream>>>(sums, out);
}

// Round 2
// 273.258 us; speedup vs baseline: 1.5539x; 1.5539x over previous
//
#include <hip/hip_runtime.h>
#include <math.h>

// Problem constants (from reference)
constexpr int N_NODES = 100000;
constexpr int N_EDGES = 3200000;
constexpr int NF      = 6;

// Binning parameters
constexpr int BSHIFT  = 11;                  // 2048 nodes per bucket
constexpr int BNODES  = 1 << BSHIFT;         // 2048
constexpr int NB      = (N_NODES + BNODES - 1) >> BSHIFT;  // 49 buckets
constexpr int CAP     = 72704;               // per-bucket capacity (mean 65536, +28 sigma)
constexpr int NSLICE  = 8;                   // accumulate slices per bucket
constexpr int TILE    = 4096;                // edges per partition block
constexpr int NBLK_PART = (N_EDGES + TILE - 1) / TILE;     // 782

// ---------------- fast-path ws layout (bytes) ----------------
// v        : N_NODES * 8                  (float2)
// msg      : NB*CAP * 8                   (float2)
// lrow     : NB*CAP * 2                   (u16)
// partials : NB*NSLICE*BNODES * 8         (float2)
// counters : gcur[NB] u32, sums[3] float  (zeroed each call)
constexpr size_t OFF_V    = 0;
constexpr size_t OFF_MSG  = OFF_V + (size_t)N_NODES * 8;                 // 800,000
constexpr size_t OFF_LROW = OFF_MSG + (size_t)NB * CAP * 8;              // +28,499,968
constexpr size_t OFF_PART = OFF_LROW + (size_t)NB * CAP * 2;             // +7,124,992
constexpr size_t OFF_CNT  = OFF_PART + (size_t)NB * NSLICE * BNODES * 8; // +6,422,528
constexpr size_t WS_NEED  = OFF_CNT + 512;

__global__ void node_prep(const float* __restrict__ pred,
                          const float* __restrict__ target,
                          const unsigned char* __restrict__ mask,
                          float2* __restrict__ v) {
    int i = blockIdx.x * blockDim.x + threadIdx.x;
    if (i >= N_NODES) return;
    const int b = i * NF;
    float vm = mask[b + 0] ? pred[b + 0] : target[b + 0];
    float va = mask[b + 1] ? pred[b + 1] : target[b + 1];
    float s, c;
    sincosf(va, &s, &c);
    v[i] = make_float2(vm * c, vm * s);
}

// Scatter each edge's message into its destination-row bucket.
__global__ __launch_bounds__(256) void partition_edges(
        const int* __restrict__ row, const int* __restrict__ col,
        const float2* __restrict__ attr, const float2* __restrict__ v,
        unsigned int* __restrict__ gcur,
        unsigned short* __restrict__ lrow, float2* __restrict__ msg) {
    __shared__ unsigned int h[4][NB];
    __shared__ unsigned int base[4][NB];
    __shared__ unsigned int cur[4][NB];
    const int tid = threadIdx.x;
    const int w = tid >> 6;
    const int e0 = blockIdx.x * TILE;

    for (int i = tid; i < 4 * NB; i += 256) {
        (&h[0][0])[i] = 0u;
        (&cur[0][0])[i] = 0u;
    }
    __syncthreads();

    int r[16];
    #pragma unroll
    for (int k = 0; k < 16; ++k) {
        int e = e0 + k * 256 + tid;
        if (e < N_EDGES) {
            r[k] = row[e];
            atomicAdd(&h[w][r[k] >> BSHIFT], 1u);
        } else {
            r[k] = -1;
        }
    }
    __syncthreads();

    for (int b = tid; b < NB; b += 256) {
        unsigned t0 = h[0][b], t1 = h[1][b], t2 = h[2][b], t3 = h[3][b];
        unsigned tot = t0 + t1 + t2 + t3;
        unsigned g = tot ? atomicAdd(&gcur[b], tot) : 0u;
        base[0][b] = g;
        base[1][b] = g + t0;
        base[2][b] = g + t0 + t1;
        base[3][b] = g + t0 + t1 + t2;
    }
    __syncthreads();

    #pragma unroll
    for (int k = 0; k < 16; ++k) {
        int e = e0 + k * 256 + tid;
        if (e >= N_EDGES) break;
        int rr = r[k];
        int b = rr >> BSHIFT;
        unsigned slot = base[w][b] + atomicAdd(&cur[w][b], 1u);
        if (slot < (unsigned)CAP) {
            int c = col[e];
            float2 gb = attr[e];
            float2 vv = v[c];
            // (G - iB) * conj(V) = (G*vr - B*vi) + i*(-(G*vi + B*vr))
            float mre = fmaf(gb.x, vv.x, -gb.y * vv.y);
            float mim = -fmaf(gb.x, vv.y, gb.y * vv.x);
            size_t idx = (size_t)b * CAP + slot;
            lrow[idx] = (unsigned short)(rr & (BNODES - 1));
            msg[idx] = make_float2(mre, mim);
        }
    }
}

// Each block: one (bucket, slice). Accumulate into LDS, write one partial.
__global__ __launch_bounds__(256) void bucket_accum(
        const unsigned int* __restrict__ gcur,
        const unsigned short* __restrict__ lrow,
        const float2* __restrict__ msg,
        float2* __restrict__ partials) {
    __shared__ float acc[BNODES][2];   // 16 KB
    const int b = blockIdx.x / NSLICE;
    const int s = blockIdx.x % NSLICE;
    int cnt = (int)min(gcur[b], (unsigned)CAP);
    for (int i = threadIdx.x; i < BNODES; i += 256) { acc[i][0] = 0.f; acc[i][1] = 0.f; }
    __syncthreads();
    int per = (cnt + NSLICE - 1) / NSLICE;
    int st = s * per;
    int en = min(st + per, cnt);
    const unsigned short* lr = lrow + (size_t)b * CAP;
    const float2* m = msg + (size_t)b * CAP;
    for (int j = st + threadIdx.x; j < en; j += 256) {
        int li = lr[j];
        float2 mm = m[j];
        atomicAdd(&acc[li][0], mm.x);
        atomicAdd(&acc[li][1], mm.y);
    }
    __syncthreads();
    float2* p = partials + (size_t)blockIdx.x * BNODES;
    for (int i = threadIdx.x; i < BNODES; i += 256)
        p[i] = make_float2(acc[i][0], acc[i][1]);
}

__global__ void finalize_nodes(const float* __restrict__ pred,
                               const float* __restrict__ target,
                               const unsigned char* __restrict__ mask,
                               const float2* __restrict__ v,
                               const float2* __restrict__ partials,
                               float* __restrict__ sums) {
    int i = blockIdx.x * blockDim.x + threadIdx.x;
    float a = 0.f, ar = 0.f, ai = 0.f;
    if (i < N_NODES) {
        const int bb = i >> BSHIFT;
        const int li = i & (BNODES - 1);
        float mr = 0.f, mi = 0.f;
        #pragma unroll
        for (int s = 0; s < NSLICE; ++s) {
            float2 p = partials[((size_t)(bb * NSLICE + s)) * BNODES + li];
            mr += p.x; mi += p.y;
        }
        const int b = i * NF;
        float pg = mask[b + 2] ? pred[b + 2] : target[b + 2];
        float qg = mask[b + 3] ? pred[b + 3] : target[b + 3];
        float pd = mask[b + 4] ? pred[b + 4] : target[b + 4];
        float qd = mask[b + 5] ? pred[b + 5] : target[b + 5];
        float netP = pg - pd;
        float netQ = qg - qd;
        float2 vv = v[i];
        float s_re = vv.x * mr - vv.y * mi;
        float s_im = vv.x * mi + vv.y * mr;
        float dre = netP - s_re;
        float dim = netQ - s_im;
        ar = fabsf(dre);
        ai = fabsf(dim);
        a  = sqrtf(dre * dre + dim * dim);
    }
    #pragma unroll
    for (int off = 32; off > 0; off >>= 1) {
        a  += __shfl_down(a,  off, 64);
        ar += __shfl_down(ar, off, 64);
        ai += __shfl_down(ai, off, 64);
    }
    __shared__ float red[3][4];
    int wave = threadIdx.x >> 6;
    int lane = threadIdx.x & 63;
    if (lane == 0) { red[0][wave] = a; red[1][wave] = ar; red[2][wave] = ai; }
    __syncthreads();
    if (threadIdx.x == 0) {
        atomicAdd(&sums[0], red[0][0] + red[0][1] + red[0][2] + red[0][3]);
        atomicAdd(&sums[1], red[1][0] + red[1][1] + red[1][2] + red[1][3]);
        atomicAdd(&sums[2], red[2][0] + red[2][1] + red[2][2] + red[2][3]);
    }
}

__global__ void write_out(const float* __restrict__ sums, float* __restrict__ out) {
    if (threadIdx.x == 0 && blockIdx.x == 0) {
        const float inv = 1.0f / (float)N_NODES;
        out[0] = sums[0] * inv;
        out[1] = sums[1] * inv;
        out[2] = sums[2] * inv;
    }
}

// ---------------- fallback (round-1 atomic path, if ws too small) ------------
__global__ void edge_scatter_fb(const int* __restrict__ row,
                                const int* __restrict__ col,
                                const float2* __restrict__ attr,
                                const float2* __restrict__ v,
                                float2* __restrict__ mv) {
    int e = blockIdx.x * blockDim.x + threadIdx.x;
    if (e >= N_EDGES) return;
    int r = row[e];
    int c = col[e];
    float2 gb = attr[e];
    float2 vv = v[c];
    float mre = fmaf(gb.x, vv.x, -gb.y * vv.y);
    float mim = -fmaf(gb.x, vv.y, gb.y * vv.x);
    atomicAdd(&mv[r].x, mre);
    atomicAdd(&mv[r].y, mim);
}

__global__ void finalize_fb(const float* __restrict__ pred,
                            const float* __restrict__ target,
                            const unsigned char* __restrict__ mask,
                            const float2* __restrict__ v,
                            const float2* __restrict__ mv,
                            float* __restrict__ sums) {
    int i = blockIdx.x * blockDim.x + threadIdx.x;
    float a = 0.f, ar = 0.f, ai = 0.f;
    if (i < N_NODES) {
        const int b = i * NF;
        float pg = mask[b + 2] ? pred[b + 2] : target[b + 2];
        float qg = mask[b + 3] ? pred[b + 3] : target[b + 3];
        float pd = mask[b + 4] ? pred[b + 4] : target[b + 4];
        float qd = mask[b + 5] ? pred[b + 5] : target[b + 5];
        float netP = pg - pd;
        float netQ = qg - qd;
        float2 vv = v[i];
        float2 m = mv[i];
        float s_re = vv.x * m.x - vv.y * m.y;
        float s_im = vv.x * m.y + vv.y * m.x;
        float dre = netP - s_re;
        float dim = netQ - s_im;
        ar = fabsf(dre);
        ai = fabsf(dim);
        a  = sqrtf(dre * dre + dim * dim);
    }
    #pragma unroll
    for (int off = 32; off > 0; off >>= 1) {
        a  += __shfl_down(a,  off, 64);
        ar += __shfl_down(ar, off, 64);
        ai += __shfl_down(ai, off, 64);
    }
    __shared__ float red[3][4];
    int wave = threadIdx.x >> 6;
    int lane = threadIdx.x & 63;
    if (lane == 0) { red[0][wave] = a; red[1][wave] = ar; red[2][wave] = ai; }
    __syncthreads();
    if (threadIdx.x == 0) {
        atomicAdd(&sums[0], red[0][0] + red[0][1] + red[0][2] + red[0][3]);
        atomicAdd(&sums[1], red[1][0] + red[1][1] + red[1][2] + red[1][3]);
        atomicAdd(&sums[2], red[2][0] + red[2][1] + red[2][2] + red[2][3]);
    }
}

extern "C" void kernel_launch(void* const* d_in, const int* in_sizes, int n_in,
                              void* d_out, int out_size, void* d_ws, size_t ws_size,
                              hipStream_t stream) {
    const float*         pred   = (const float*)d_in[0];
    const float*         target = (const float*)d_in[1];
    const int*           eidx   = (const int*)d_in[2];      // (2, N_EDGES)
    const float2*        attr   = (const float2*)d_in[3];   // (N_EDGES, 2)
    const unsigned char* mask   = (const unsigned char*)d_in[4];
    float* out = (float*)d_out;

    const int* row = eidx;             // edge_index[0] = src
    const int* col = eidx + N_EDGES;   // edge_index[1] = dst

    char* ws = (char*)d_ws;
    const int B = 256;

    if (ws_size >= WS_NEED) {
        float2*         v        = (float2*)(ws + OFF_V);
        float2*         msg      = (float2*)(ws + OFF_MSG);
        unsigned short* lrow     = (unsigned short*)(ws + OFF_LROW);
        float2*         partials = (float2*)(ws + OFF_PART);
        unsigned int*   gcur     = (unsigned int*)(ws + OFF_CNT);
        float*          sums     = (float*)(ws + OFF_CNT + NB * sizeof(unsigned int));

        hipMemsetAsync(ws + OFF_CNT, 0, 512, stream);
        node_prep<<<(N_NODES + B - 1) / B, B, 0, stream>>>(pred, target, mask, v);
        partition_edges<<<NBLK_PART, B, 0, stream>>>(row, col, attr, v, gcur, lrow, msg);
        bucket_accum<<<NB * NSLICE, B, 0, stream>>>(gcur, lrow, msg, partials);
        finalize_nodes<<<(N_NODES + B - 1) / B, B, 0, stream>>>(pred, target, mask, v,
                                                                partials, sums);
        write_out<<<1, 64, 0, stream>>>(sums, out);
    } else {
        // fallback: round-1 structure
        float2* v    = (float2*)ws;
        float2* mv   = (float2*)(ws + (size_t)N_NODES * 8);
        float*  sums = (float*)(ws + 2ull * N_NODES * 8);
        hipMemsetAsync(mv, 0, (size_t)N_NODES * 8 + 16, stream);
        node_prep<<<(N_NODES + B - 1) / B, B, 0, stream>>>(pred, target, mask, v);
        edge_scatter_fb<<<(N_EDGES + B - 1) / B, B, 0, stream>>>(row, col, attr, v, mv);
        finalize_fb<<<(N_NODES + B - 1) / B, B, 0, stream>>>(pred, target, mask, v, mv, sums);
        write_out<<<1, 64, 0, stream>>>(sums, out);
    }
}

// Round 3
// 220.924 us; speedup vs baseline: 1.9219x; 1.2369x over previous
//
#include <hip/hip_runtime.h>
#include <math.h>

// Problem constants (from reference)
constexpr int N_NODES = 100000;
constexpr int N_EDGES = 3200000;
constexpr int NF      = 6;

// Binning parameters
constexpr int BSHIFT  = 10;                  // 1024 nodes per bucket
constexpr int BNODES  = 1 << BSHIFT;         // 1024
constexpr int NB      = (N_NODES + BNODES - 1) >> BSHIFT;  // 98 buckets
constexpr int CAP     = 36864;               // per-bucket capacity (mean 32768, +22 sigma)
constexpr int NSLICE  = 8;                   // accumulate slices per bucket
constexpr int TILE    = 2048;                // edges per partition block
constexpr int EPT     = TILE / 256;          // 8 edges per thread
constexpr int NBLK_PART = (N_EDGES + TILE - 1) / TILE;     // 1563

// ---------------- fast-path ws layout (bytes) ----------------
constexpr size_t OFF_V    = 0;
constexpr size_t OFF_MSG  = OFF_V + (size_t)N_NODES * 8;
constexpr size_t OFF_LROW = OFF_MSG + (size_t)NB * CAP * 8;
constexpr size_t OFF_PART = OFF_LROW + (size_t)NB * CAP * 2;
constexpr size_t OFF_CNT  = OFF_PART + (size_t)NB * NSLICE * BNODES * 8;
constexpr size_t OFF_SUMS = OFF_CNT + 400;   // NB*4 = 392 <= 400
constexpr size_t WS_NEED  = OFF_CNT + 512;

__global__ void node_prep(const float* __restrict__ pred,
                          const float* __restrict__ target,
                          const unsigned char* __restrict__ mask,
                          float2* __restrict__ v) {
    int i = blockIdx.x * blockDim.x + threadIdx.x;
    if (i >= N_NODES) return;
    const int b = i * NF;
    float vm = mask[b + 0] ? pred[b + 0] : target[b + 0];
    float va = mask[b + 1] ? pred[b + 1] : target[b + 1];
    float s, c;
    sincosf(va, &s, &c);
    v[i] = make_float2(vm * c, vm * s);
}

// Scatter each edge's message into its destination-row bucket, staged through
// LDS so global writes are contiguous per (block, bucket) chunk.
__global__ __launch_bounds__(256) void partition_edges(
        const int* __restrict__ row, const int* __restrict__ col,
        const float2* __restrict__ attr, const float2* __restrict__ v,
        unsigned int* __restrict__ gcur,
        unsigned short* __restrict__ lrow_g, float2* __restrict__ msg_g) {
    __shared__ unsigned int h[4][NB];     // per-wave histogram
    __shared__ unsigned int cur[4][NB];   // per-wave placement cursor
    __shared__ int wb[4][NB];             // per-wave LDS base slot
    __shared__ int dbase[NB];             // gbase - lbase
    __shared__ unsigned int tot_s[NB];
    __shared__ unsigned int rr_s[TILE];   // staged row ids (sorted by bucket)
    __shared__ float2 msg_s[TILE];        // staged messages
    __shared__ int total_s;

    const int tid = threadIdx.x;
    const int w = tid >> 6;
    const int e0 = blockIdx.x * TILE;

    for (int i = tid; i < 4 * NB; i += 256) {
        (&h[0][0])[i] = 0u;
        (&cur[0][0])[i] = 0u;
    }
    __syncthreads();

    // Phase 1: histogram (keep row ids in registers)
    int r[EPT];
    #pragma unroll
    for (int k = 0; k < EPT; ++k) {
        int e = e0 + k * 256 + tid;
        if (e < N_EDGES) {
            r[k] = row[e];
            atomicAdd(&h[w][r[k] >> BSHIFT], 1u);
        } else {
            r[k] = -1;
        }
    }
    __syncthreads();

    // Phase 2: per-bucket totals
    if (tid < NB)
        tot_s[tid] = h[0][tid] + h[1][tid] + h[2][tid] + h[3][tid];
    __syncthreads();

    // Phase 3: exclusive scan (per-thread O(b) — NB=98, cheap), reserve global
    if (tid < NB) {
        int lbase = 0;
        for (int j = 0; j < tid; ++j) lbase += (int)tot_s[j];
        unsigned t0 = h[0][tid], t1 = h[1][tid], t2 = h[2][tid];
        unsigned tot = tot_s[tid];
        unsigned g = tot ? atomicAdd(&gcur[tid], tot) : 0u;
        dbase[tid] = (int)g - lbase;
        wb[0][tid] = lbase;
        wb[1][tid] = lbase + (int)t0;
        wb[2][tid] = lbase + (int)(t0 + t1);
        wb[3][tid] = lbase + (int)(t0 + t1 + t2);
        if (tid == NB - 1) total_s = lbase + (int)tot;
    }
    __syncthreads();

    // Phase 4: compute messages, place into sorted LDS slots
    #pragma unroll
    for (int k = 0; k < EPT; ++k) {
        int rr = r[k];
        if (rr < 0) continue;
        int e = e0 + k * 256 + tid;
        int b = rr >> BSHIFT;
        int slot = wb[w][b] + (int)atomicAdd(&cur[w][b], 1u);
        int c = col[e];
        float2 gb = attr[e];
        float2 vv = v[c];
        // (G - iB) * conj(V) = (G*vr - B*vi) + i*(-(G*vi + B*vr))
        float mre = fmaf(gb.x, vv.x, -gb.y * vv.y);
        float mim = -fmaf(gb.x, vv.y, gb.y * vv.x);
        rr_s[slot] = (unsigned)rr;
        msg_s[slot] = make_float2(mre, mim);
    }
    __syncthreads();

    // Phase 5: coalesced flush in slot order
    const int total = total_s;
    for (int j = tid; j < total; j += 256) {
        unsigned rr = rr_s[j];
        int b = (int)(rr >> BSHIFT);
        int g = dbase[b] + j;
        if (g < CAP) {
            size_t idx = (size_t)b * CAP + g;
            msg_g[idx] = msg_s[j];
            lrow_g[idx] = (unsigned short)(rr & (BNODES - 1));
        }
    }
}

// Each block: one (bucket, slice). Accumulate into LDS, write one partial.
__global__ __launch_bounds__(256) void bucket_accum(
        const unsigned int* __restrict__ gcur,
        const unsigned short* __restrict__ lrow,
        const float2* __restrict__ msg,
        float2* __restrict__ partials) {
    __shared__ float acc[BNODES][2];   // 8 KB
    const int b = blockIdx.x / NSLICE;
    const int s = blockIdx.x % NSLICE;
    int cnt = (int)min(gcur[b], (unsigned)CAP);
    for (int i = threadIdx.x; i < BNODES; i += 256) { acc[i][0] = 0.f; acc[i][1] = 0.f; }
    __syncthreads();
    int per = (cnt + NSLICE - 1) / NSLICE;
    int st = s * per;
    int en = min(st + per, cnt);
    const unsigned short* lr = lrow + (size_t)b * CAP;
    const float2* m = msg + (size_t)b * CAP;
    for (int j = st + threadIdx.x; j < en; j += 256) {
        int li = lr[j];
        float2 mm = m[j];
        atomicAdd(&acc[li][0], mm.x);
        atomicAdd(&acc[li][1], mm.y);
    }
    __syncthreads();
    float2* p = partials + (size_t)blockIdx.x * BNODES;
    for (int i = threadIdx.x; i < BNODES; i += 256)
        p[i] = make_float2(acc[i][0], acc[i][1]);
}

__global__ void finalize_nodes(const float* __restrict__ pred,
                               const float* __restrict__ target,
                               const unsigned char* __restrict__ mask,
                               const float2* __restrict__ v,
                               const float2* __restrict__ partials,
                               float* __restrict__ sums) {
    int i = blockIdx.x * blockDim.x + threadIdx.x;
    float a = 0.f, ar = 0.f, ai = 0.f;
    if (i < N_NODES) {
        const int bb = i >> BSHIFT;
        const int li = i & (BNODES - 1);
        float mr = 0.f, mi = 0.f;
        #pragma unroll
        for (int s = 0; s < NSLICE; ++s) {
            float2 p = partials[((size_t)(bb * NSLICE + s)) * BNODES + li];
            mr += p.x; mi += p.y;
        }
        const int b = i * NF;
        float pg = mask[b + 2] ? pred[b + 2] : target[b + 2];
        float qg = mask[b + 3] ? pred[b + 3] : target[b + 3];
        float pd = mask[b + 4] ? pred[b + 4] : target[b + 4];
        float qd = mask[b + 5] ? pred[b + 5] : target[b + 5];
        float netP = pg - pd;
        float netQ = qg - qd;
        float2 vv = v[i];
        float s_re = vv.x * mr - vv.y * mi;
        float s_im = vv.x * mi + vv.y * mr;
        float dre = netP - s_re;
        float dim = netQ - s_im;
        ar = fabsf(dre);
        ai = fabsf(dim);
        a  = sqrtf(dre * dre + dim * dim);
    }
    #pragma unroll
    for (int off = 32; off > 0; off >>= 1) {
        a  += __shfl_down(a,  off, 64);
        ar += __shfl_down(ar, off, 64);
        ai += __shfl_down(ai, off, 64);
    }
    __shared__ float red[3][4];
    int wave = threadIdx.x >> 6;
    int lane = threadIdx.x & 63;
    if (lane == 0) { red[0][wave] = a; red[1][wave] = ar; red[2][wave] = ai; }
    __syncthreads();
    if (threadIdx.x == 0) {
        atomicAdd(&sums[0], red[0][0] + red[0][1] + red[0][2] + red[0][3]);
        atomicAdd(&sums[1], red[1][0] + red[1][1] + red[1][2] + red[1][3]);
        atomicAdd(&sums[2], red[2][0] + red[2][1] + red[2][2] + red[2][3]);
    }
}

__global__ void write_out(const float* __restrict__ sums, float* __restrict__ out) {
    if (threadIdx.x == 0 && blockIdx.x == 0) {
        const float inv = 1.0f / (float)N_NODES;
        out[0] = sums[0] * inv;
        out[1] = sums[1] * inv;
        out[2] = sums[2] * inv;
    }
}

// ---------------- fallback (atomic path, if ws too small) ------------
__global__ void edge_scatter_fb(const int* __restrict__ row,
                                const int* __restrict__ col,
                                const float2* __restrict__ attr,
                                const float2* __restrict__ v,
                                float2* __restrict__ mv) {
    int e = blockIdx.x * blockDim.x + threadIdx.x;
    if (e >= N_EDGES) return;
    int r = row[e];
    int c = col[e];
    float2 gb = attr[e];
    float2 vv = v[c];
    float mre = fmaf(gb.x, vv.x, -gb.y * vv.y);
    float mim = -fmaf(gb.x, vv.y, gb.y * vv.x);
    atomicAdd(&mv[r].x, mre);
    atomicAdd(&mv[r].y, mim);
}

__global__ void finalize_fb(const float* __restrict__ pred,
                            const float* __restrict__ target,
                            const unsigned char* __restrict__ mask,
                            const float2* __restrict__ v,
                            const float2* __restrict__ mv,
                            float* __restrict__ sums) {
    int i = blockIdx.x * blockDim.x + threadIdx.x;
    float a = 0.f, ar = 0.f, ai = 0.f;
    if (i < N_NODES) {
        const int b = i * NF;
        float pg = mask[b + 2] ? pred[b + 2] : target[b + 2];
        float qg = mask[b + 3] ? pred[b + 3] : target[b + 3];
        float pd = mask[b + 4] ? pred[b + 4] : target[b + 4];
        float qd = mask[b + 5] ? pred[b + 5] : target[b + 5];
        float netP = pg - pd;
        float netQ = qg - qd;
        float2 vv = v[i];
        float2 m = mv[i];
        float s_re = vv.x * m.x - vv.y * m.y;
        float s_im = vv.x * m.y + vv.y * m.x;
        float dre = netP - s_re;
        float dim = netQ - s_im;
        ar = fabsf(dre);
        ai = fabsf(dim);
        a  = sqrtf(dre * dre + dim * dim);
    }
    #pragma unroll
    for (int off = 32; off > 0; off >>= 1) {
        a  += __shfl_down(a,  off, 64);
        ar += __shfl_down(ar, off, 64);
        ai += __shfl_down(ai, off, 64);
    }
    __shared__ float red[3][4];
    int wave = threadIdx.x >> 6;
    int lane = threadIdx.x & 63;
    if (lane == 0) { red[0][wave] = a; red[1][wave] = ar; red[2][wave] = ai; }
    __syncthreads();
    if (threadIdx.x == 0) {
        atomicAdd(&sums[0], red[0][0] + red[0][1] + red[0][2] + red[0][3]);
        atomicAdd(&sums[1], red[1][0] + red[1][1] + red[1][2] + red[1][3]);
        atomicAdd(&sums[2], red[2][0] + red[2][1] + red[2][2] + red[2][3]);
    }
}

extern "C" void kernel_launch(void* const* d_in, const int* in_sizes, int n_in,
                              void* d_out, int out_size, void* d_ws, size_t ws_size,
                              hipStream_t stream) {
    const float*         pred   = (const float*)d_in[0];
    const float*         target = (const float*)d_in[1];
    const int*           eidx   = (const int*)d_in[2];      // (2, N_EDGES)
    const float2*        attr   = (const float2*)d_in[3];   // (N_EDGES, 2)
    const unsigned char* mask   = (const unsigned char*)d_in[4];
    float* out = (float*)d_out;

    const int* row = eidx;             // edge_index[0] = src
    const int* col = eidx + N_EDGES;   // edge_index[1] = dst

    char* ws = (char*)d_ws;
    const int B = 256;

    if (ws_size >= WS_NEED) {
        float2*         v        = (float2*)(ws + OFF_V);
        float2*         msg      = (float2*)(ws + OFF_MSG);
        unsigned short* lrow     = (unsigned short*)(ws + OFF_LROW);
        float2*         partials = (float2*)(ws + OFF_PART);
        unsigned int*   gcur     = (unsigned int*)(ws + OFF_CNT);
        float*          sums     = (float*)(ws + OFF_SUMS);

        hipMemsetAsync(ws + OFF_CNT, 0, 512, stream);
        node_prep<<<(N_NODES + B - 1) / B, B, 0, stream>>>(pred, target, mask, v);
        partition_edges<<<NBLK_PART, B, 0, stream>>>(row, col, attr, v, gcur, lrow, msg);
        bucket_accum<<<NB * NSLICE, B, 0, stream>>>(gcur, lrow, msg, partials);
        finalize_nodes<<<(N_NODES + B - 1) / B, B, 0, stream>>>(pred, target, mask, v,
                                                                partials, sums);
        write_out<<<1, 64, 0, stream>>>(sums, out);
    } else {
        // fallback
        float2* v    = (float2*)ws;
        float2* mv   = (float2*)(ws + (size_t)N_NODES * 8);
        float*  sums = (float*)(ws + 2ull * N_NODES * 8);
        hipMemsetAsync(mv, 0, (size_t)N_NODES * 8 + 16, stream);
        node_prep<<<(N_NODES + B - 1) / B, B, 0, stream>>>(pred, target, mask, v);
        edge_scatter_fb<<<(N_EDGES + B - 1) / B, B, 0, stream>>>(row, col, attr, v, mv);
        finalize_fb<<<(N_NODES + B - 1) / B, B, 0, stream>>>(pred, target, mask, v, mv, sums);
        write_out<<<1, 64, 0, stream>>>(sums, out);
    }
}